// Round 1
// baseline (296.748 us; speedup 1.0000x reference)
//
#include <hip/hip_runtime.h>

typedef __attribute__((ext_vector_type(4))) float f32x4;
typedef __attribute__((ext_vector_type(8))) short bf16x8;  // 8 bf16 = 4 VGPRs

#define HDIM 128

// fp32 -> bf16 round-to-nearest-even (bit trick; avoids hip_bf16 API variance)
__device__ __forceinline__ short f2bf(float f) {
  union { float fv; unsigned u; } v; v.fv = f;
  unsigned u = v.u;
  u += 0x7fffu + ((u >> 16) & 1u);
  return (short)(u >> 16);
}

// out[b][g] = sum_k h[b][k] * W[g][k] + x[b][g]
// MFMA: A = W (M-dim = g), B = h^T (N-dim = b), D = 16x16 tile, K = 128 in 4 steps.
// C/D layout (verified): col = lane&15 -> b, row = (lane>>4)*4 + reg -> g
//   => each lane's 4 acc regs are 4 contiguous g's of one output row: float4 I/O.
__global__ __launch_bounds__(256) void lrc_mfma_kernel(
    const float* __restrict__ xp,
    const float* __restrict__ hp,
    const float* __restrict__ Wp,
    float* __restrict__ outp,
    int num_tiles)  // tiles of 64 rows (4 waves x 16 rows)
{
  __shared__ short wlds[32 * 64 * 8];  // 32 frags x 64 lanes x 8 bf16 = 32 KB

  const int tid  = (int)threadIdx.x;
  const int wave = tid >> 6;
  const int lane = tid & 63;
  const int l15  = lane & 15;
  const int lq   = lane >> 4;

  // ---- Stage W as 32 bf16 A-fragments in LDS (once per block). f = gt*4 + kt ----
  // A-frag: lane holds W[gt*16 + (lane&15)][kt*32 + (lane>>4)*8 + e], e=0..7 (row-contiguous read)
  #pragma unroll
  for (int i = 0; i < 8; ++i) {
    const int f  = wave * 8 + i;
    const int gt = f >> 2;
    const int kt = f & 3;
    const float* wrow = Wp + (gt * 16 + l15) * HDIM + kt * 32 + lq * 8;
    const f32x4 w0 = *(const f32x4*)(wrow);
    const f32x4 w1 = *(const f32x4*)(wrow + 4);
    bf16x8 wf;
    wf[0] = f2bf(w0[0]); wf[1] = f2bf(w0[1]); wf[2] = f2bf(w0[2]); wf[3] = f2bf(w0[3]);
    wf[4] = f2bf(w1[0]); wf[5] = f2bf(w1[1]); wf[6] = f2bf(w1[2]); wf[7] = f2bf(w1[3]);
    *(bf16x8*)(&wlds[(f * 64 + lane) * 8]) = wf;  // lane-contiguous: conflict-free b128
  }
  __syncthreads();

  for (int bt = (int)blockIdx.x; bt < num_tiles; bt += (int)gridDim.x) {
    const int row = bt * 64 + wave * 16 + l15;   // this lane's batch row
    const float* hrow = hp + (long)row * HDIM;

    // B-operand fragments from h: lane holds h[row][kt*32 + lq*8 + e] (contiguous 32B)
    bf16x8 hf[4];
    #pragma unroll
    for (int kt = 0; kt < 4; ++kt) {
      const f32x4 a = *(const f32x4*)(hrow + kt * 32 + lq * 8);
      const f32x4 b = *(const f32x4*)(hrow + kt * 32 + lq * 8 + 4);
      hf[kt][0] = f2bf(a[0]); hf[kt][1] = f2bf(a[1]);
      hf[kt][2] = f2bf(a[2]); hf[kt][3] = f2bf(a[3]);
      hf[kt][4] = f2bf(b[0]); hf[kt][5] = f2bf(b[1]);
      hf[kt][6] = f2bf(b[2]); hf[kt][7] = f2bf(b[3]);
    }

    // Prefetch x (same addresses as the stores)
    const float* xrow = xp + (long)row * HDIM;
    f32x4 xv[8];
    #pragma unroll
    for (int gt = 0; gt < 8; ++gt)
      xv[gt] = *(const f32x4*)(xrow + gt * 16 + lq * 4);

    float* orow = outp + (long)row * HDIM;
    #pragma unroll
    for (int gt = 0; gt < 8; ++gt) {
      f32x4 acc = {0.f, 0.f, 0.f, 0.f};
      #pragma unroll
      for (int kt = 0; kt < 4; ++kt) {
        const bf16x8 wf = *(const bf16x8*)(&wlds[((gt * 4 + kt) * 64 + lane) * 8]);
        acc = __builtin_amdgcn_mfma_f32_16x16x32_bf16(wf, hf[kt], acc, 0, 0, 0);
      }
      acc += xv[gt];
      *(f32x4*)(orow + gt * 16 + lq * 4) = acc;
    }
  }
}

extern "C" void kernel_launch(void* const* d_in, const int* in_sizes, int n_in,
                              void* d_out, int out_size, void* d_ws, size_t ws_size,
                              hipStream_t stream) {
  const float* xp = (const float*)d_in[0];  // x_projected_t (B,H) fp32
  const float* hp = (const float*)d_in[1];  // h_prev        (B,H) fp32
  const float* Wp = (const float*)d_in[2];  // W_hh          (H,H) fp32
  float* op = (float*)d_out;                // h_next        (B,H) fp32

  const int B = in_sizes[0] / HDIM;         // 1048576
  const int num_tiles = B / 64;             // 16384 (exact, B % 64 == 0)
  const int grid = 2048;                    // grid-stride: 8 tiles/block, amortizes W staging

  hipLaunchKernelGGL(lrc_mfma_kernel, dim3(grid), dim3(256), 0, stream,
                     xp, hp, Wp, op, num_tiles);
}